// Round 10
// baseline (166.534 us; speedup 1.0000x reference)
//
#include <hip/hip_runtime.h>

#define BATCH 32768
#define HID 256
#define ACT 32
#define NROWS 40960

#define TBL_BYTES ((size_t)NROWS * HID * 2)       // 20,971,520 (bf16, group-major)
#define ACT_BYTES ((size_t)BATCH * 512 * 4)       // 67,108,864 (fp32 activations)

typedef float v4f __attribute__((ext_vector_type(4)));

// ============ kernel 0: fp32 [40960][256] -> bf16 group-major [8][40960][32] ============
__global__ __launch_bounds__(256) void nnue_cvt_kernel(
    const float* __restrict__ ft_w, unsigned short* __restrict__ tbl)
{
    const int g  = blockIdx.y;                       // 0..7
    const int tx = blockIdx.x * 256 + threadIdx.x;   // 0 .. 40960*4-1
    const int row = tx >> 2;
    const int c8  = tx & 3;                          // 8-channel chunk within 32-ch group
    const float* __restrict__ src = ft_w + (size_t)row * HID + g * 32 + c8 * 8;
    unsigned int o[8];
    #pragma unroll
    for (int j = 0; j < 8; ++j) {
        unsigned int u = __float_as_uint(src[j]);
        u = u + 0x7FFFu + ((u >> 16) & 1u);          // round-to-nearest-even bf16
        o[j] = u >> 16;
    }
    uint4 pack;
    pack.x = o[0] | (o[1] << 16);
    pack.y = o[2] | (o[3] << 16);
    pack.z = o[4] | (o[5] << 16);
    pack.w = o[6] | (o[7] << 16);
    *(uint4*)(tbl + ((size_t)g * NROWS + row) * 32 + c8 * 8) = pack;
}

// ============ kernel 1: FT gather v2 — 16B/lane, half the VMEM instructions ============
// Block: 256 threads = 64 positions x 4 chunks. One 32-channel group per block.
// Lane (p, c4) owns channels [g*32 + c4*8 .. +7]; serially accumulates all 64 rows.
// Row-group = 64B (4 lanes x 16B) -> same L2 request count as round 9, but each
// wave-load instruction covers 16 rows instead of 8 (half the VMEM instructions).
#define LDU4(o) (*(const uint4*)(tg + (unsigned int)(o) + cb))

__global__ __launch_bounds__(256, 6) void nnue_ft_kernel(
    const int* __restrict__ widx, const int* __restrict__ bidx,
    const float* __restrict__ stm,
    const unsigned short* __restrict__ tbl, const float* __restrict__ ft_b,
    float* __restrict__ act)
{
    const int bid = blockIdx.x;
    const int g   = bid & 7;           // column group -> XCD (round-robin dispatch)
    const int pt  = bid >> 3;          // tile of 64 positions
    const int t   = threadIdx.x;
    const int p   = t >> 2;            // position slot 0..63
    const int c4  = t & 3;             // 16B chunk (8 channels) 0..3

    __shared__ int   soff[64][68];     // byte offsets rowid*64, padded stride
    __shared__ float sstm[64];

    // stage 64 positions x 64 indices as byte offsets, coalesced
    #pragma unroll
    for (int k = 0; k < 16; ++k) {
        const int u  = t + k * 256;            // 0..4095
        const int pp = u >> 6, rr = u & 63;
        const int pos = pt * 64 + pp;
        int v;
        if (rr < 32) v = widx[(size_t)pos * ACT + rr];
        else         v = bidx[(size_t)pos * ACT + (rr - 32)];
        soff[pp][rr] = v << 6;
    }
    if (t < 64) sstm[t] = stm[pt * 64 + t];
    __syncthreads();

    const char* __restrict__ tg = (const char*)(tbl + (size_t)g * NROWS * 32);
    const unsigned int cb = (unsigned int)(c4 << 4);
    const int4* __restrict__ sview = (const int4*)(&soff[p][0]);

    float wa[8] = {0.f,0.f,0.f,0.f,0.f,0.f,0.f,0.f};
    float ba[8] = {0.f,0.f,0.f,0.f,0.f,0.f,0.f,0.f};

    // white rows: int4 slots 0..7 (4 batches x 8 rows)
    #pragma unroll
    for (int blk = 0; blk < 4; ++blk) {
        const int4 oA = sview[blk * 2];
        const int4 oB = sview[blk * 2 + 1];
        uint4 v[8];
        v[0] = LDU4(oA.x); v[1] = LDU4(oA.y); v[2] = LDU4(oA.z); v[3] = LDU4(oA.w);
        v[4] = LDU4(oB.x); v[5] = LDU4(oB.y); v[6] = LDU4(oB.z); v[7] = LDU4(oB.w);
        #pragma unroll
        for (int i = 0; i < 8; ++i) {
            wa[0] += __uint_as_float(v[i].x << 16);
            wa[1] += __uint_as_float(v[i].x & 0xFFFF0000u);
            wa[2] += __uint_as_float(v[i].y << 16);
            wa[3] += __uint_as_float(v[i].y & 0xFFFF0000u);
            wa[4] += __uint_as_float(v[i].z << 16);
            wa[5] += __uint_as_float(v[i].z & 0xFFFF0000u);
            wa[6] += __uint_as_float(v[i].w << 16);
            wa[7] += __uint_as_float(v[i].w & 0xFFFF0000u);
        }
    }
    // black rows: int4 slots 8..15
    #pragma unroll
    for (int blk = 4; blk < 8; ++blk) {
        const int4 oA = sview[blk * 2];
        const int4 oB = sview[blk * 2 + 1];
        uint4 v[8];
        v[0] = LDU4(oA.x); v[1] = LDU4(oA.y); v[2] = LDU4(oA.z); v[3] = LDU4(oA.w);
        v[4] = LDU4(oB.x); v[5] = LDU4(oB.y); v[6] = LDU4(oB.z); v[7] = LDU4(oB.w);
        #pragma unroll
        for (int i = 0; i < 8; ++i) {
            ba[0] += __uint_as_float(v[i].x << 16);
            ba[1] += __uint_as_float(v[i].x & 0xFFFF0000u);
            ba[2] += __uint_as_float(v[i].y << 16);
            ba[3] += __uint_as_float(v[i].y & 0xFFFF0000u);
            ba[4] += __uint_as_float(v[i].z << 16);
            ba[5] += __uint_as_float(v[i].z & 0xFFFF0000u);
            ba[6] += __uint_as_float(v[i].w << 16);
            ba[7] += __uint_as_float(v[i].w & 0xFFFF0000u);
        }
    }

    const float4 bv0 = ((const float4*)ft_b)[g * 8 + c4 * 2];
    const float4 bv1 = ((const float4*)ft_b)[g * 8 + c4 * 2 + 1];

    v4f w0, w1, z0, z1;
    w0.x = fminf(fmaxf(wa[0] + bv0.x, 0.f), 1.f);
    w0.y = fminf(fmaxf(wa[1] + bv0.y, 0.f), 1.f);
    w0.z = fminf(fmaxf(wa[2] + bv0.z, 0.f), 1.f);
    w0.w = fminf(fmaxf(wa[3] + bv0.w, 0.f), 1.f);
    w1.x = fminf(fmaxf(wa[4] + bv1.x, 0.f), 1.f);
    w1.y = fminf(fmaxf(wa[5] + bv1.y, 0.f), 1.f);
    w1.z = fminf(fmaxf(wa[6] + bv1.z, 0.f), 1.f);
    w1.w = fminf(fmaxf(wa[7] + bv1.w, 0.f), 1.f);
    z0.x = fminf(fmaxf(ba[0] + bv0.x, 0.f), 1.f);
    z0.y = fminf(fmaxf(ba[1] + bv0.y, 0.f), 1.f);
    z0.z = fminf(fmaxf(ba[2] + bv0.z, 0.f), 1.f);
    z0.w = fminf(fmaxf(ba[3] + bv0.w, 0.f), 1.f);
    z1.x = fminf(fmaxf(ba[4] + bv1.x, 0.f), 1.f);
    z1.y = fminf(fmaxf(ba[5] + bv1.y, 0.f), 1.f);
    z1.z = fminf(fmaxf(ba[6] + bv1.z, 0.f), 1.f);
    z1.w = fminf(fmaxf(ba[7] + bv1.w, 0.f), 1.f);

    const int  pos = pt * 64 + p;
    const bool s   = (sstm[p] != 0.0f);
    float* dst = act + (size_t)pos * 512 + g * 32 + c4 * 8;
    // Non-temporal: act is write-once streaming; keep the table resident in L2.
    __builtin_nontemporal_store(w0, (v4f*)(dst     + (s ? 0 : 256)));
    __builtin_nontemporal_store(w1, (v4f*)(dst + 4 + (s ? 0 : 256)));
    __builtin_nontemporal_store(z0, (v4f*)(dst     + (s ? 256 : 0)));
    __builtin_nontemporal_store(z1, (v4f*)(dst + 4 + (s ? 256 : 0)));
}

// ============ kernel 2: MLP (8 positions per block, round-4 proven shape) ============
__global__ __launch_bounds__(256, 4) void nnue_mlp_kernel(
    const float* __restrict__ act,
    const float* __restrict__ l1_w, const float* __restrict__ l1_b,
    const float* __restrict__ l2_w, const float* __restrict__ l2_b,
    const float* __restrict__ l3_w, const float* __restrict__ l3_b,
    float* __restrict__ out)
{
    const int bb = blockIdx.x;       // positions bb*8 .. bb*8+7
    const int t  = threadIdx.x;

    __shared__ float4 sact[8 * 128]; // 8 positions x 512 fp32 = 16 KB
    __shared__ float  x1s[8][33];
    __shared__ float  x2s[8][33];

    const float4* __restrict__ ga = (const float4*)(act + (size_t)bb * 8 * 512);
    #pragma unroll
    for (int k = 0; k < 4; ++k) sact[t + k * 256] = ga[t + k * 256];
    __syncthreads();

    // L1: 32 outputs x 512-dot, 8 threads/output, 8 positions
    {
        const int o  = t >> 3;
        const int l8 = t & 7;
        const float4* __restrict__ wrow = (const float4*)(l1_w + o * 512);
        float pacc[8] = {0.f,0.f,0.f,0.f,0.f,0.f,0.f,0.f};
        #pragma unroll
        for (int j = 0; j < 16; ++j) {
            const int i4 = l8 + j * 8;
            const float4 wv = wrow[i4];
            #pragma unroll
            for (int p = 0; p < 8; ++p) {
                const float4 a = sact[p * 128 + i4];
                pacc[p] += wv.x*a.x + wv.y*a.y + wv.z*a.z + wv.w*a.w;
            }
        }
        #pragma unroll
        for (int p = 0; p < 8; ++p) {
            pacc[p] += __shfl_down(pacc[p], 4, 8);
            pacc[p] += __shfl_down(pacc[p], 2, 8);
            pacc[p] += __shfl_down(pacc[p], 1, 8);
        }
        if (l8 == 0) {
            const float bo = l1_b[o];
            #pragma unroll
            for (int p = 0; p < 8; ++p)
                x1s[p][o] = fminf(fmaxf(pacc[p] + bo, 0.f), 1.f);
        }
    }
    __syncthreads();

    // L2: 256 threads = 8 positions x 32 outputs
    {
        const int p  = t >> 5;
        const int oo = t & 31;
        const float* __restrict__ wr = l2_w + oo * 32;
        float s2 = l2_b[oo];
        #pragma unroll
        for (int j = 0; j < 32; ++j) s2 += x1s[p][j] * wr[j];
        x2s[p][oo] = fminf(fmaxf(s2, 0.f), 1.f);
    }
    __syncthreads();

    // L3
    if (t < 8) {
        float s3 = l3_b[0];
        #pragma unroll
        for (int j = 0; j < 32; ++j) s3 += x2s[t][j] * l3_w[j];
        out[bb * 8 + t] = s3;
    }
}

// ============ fallback (round-3 kernel) if ws_size is insufficient ============
__device__ __forceinline__ float4 clip4(float4 v) {
    v.x = fminf(fmaxf(v.x, 0.0f), 1.0f);
    v.y = fminf(fmaxf(v.y, 0.0f), 1.0f);
    v.z = fminf(fmaxf(v.z, 0.0f), 1.0f);
    v.w = fminf(fmaxf(v.w, 0.0f), 1.0f);
    return v;
}
__device__ __forceinline__ void acc4(float4& a, const float4 v) {
    a.x += v.x; a.y += v.y; a.z += v.z; a.w += v.w;
}

__global__ __launch_bounds__(256, 4) void nnue_fwd_fallback(
    const int* __restrict__ widx, const int* __restrict__ bidx,
    const float* __restrict__ stm,
    const float* __restrict__ ft_w, const float* __restrict__ ft_b,
    const float* __restrict__ l1_w, const float* __restrict__ l1_b,
    const float* __restrict__ l2_w, const float* __restrict__ l2_b,
    const float* __restrict__ l3_w, const float* __restrict__ l3_b,
    float* __restrict__ out)
{
    const int bb = blockIdx.x;
    const int t  = threadIdx.x;
    const int w  = t >> 6;
    const int q  = t & 63;

    __shared__ float4 accbuf[4][128];
    __shared__ float  x1s[4][32];
    __shared__ float  x2s[4][32];

    const int pos = bb * 4 + w;
    int myidx;
    if (q < 32) myidx = widx[pos * ACT + q];
    else        myidx = bidx[pos * ACT + (q - 32)];

    const float4* __restrict__ ftw4 = (const float4*)ft_w;
    const float4  bias = ((const float4*)ft_b)[q];
    float4 accW = bias, accB = bias;

    #pragma unroll
    for (int r0 = 0; r0 < 32; r0 += 8) {
        float4 vw[8], vb[8];
        #pragma unroll
        for (int i = 0; i < 8; ++i) {
            const int rw = __builtin_amdgcn_readlane(myidx, r0 + i);
            vw[i] = ftw4[(size_t)rw * 64 + q];
        }
        #pragma unroll
        for (int i = 0; i < 8; ++i) {
            const int rb = __builtin_amdgcn_readlane(myidx, 32 + r0 + i);
            vb[i] = ftw4[(size_t)rb * 64 + q];
        }
        #pragma unroll
        for (int i = 0; i < 8; ++i) { acc4(accW, vw[i]); acc4(accB, vb[i]); }
    }

    const bool s = (stm[pos] != 0.0f);
    accbuf[w][(s ? 0 : 64) + q] = clip4(accW);
    accbuf[w][(s ? 64 : 0) + q] = clip4(accB);
    __syncthreads();

    {
        const int o  = t >> 3;
        const int l8 = t & 7;
        const float4* __restrict__ wrow = (const float4*)(l1_w + o * 512);
        float p0 = 0.f, p1 = 0.f, p2 = 0.f, p3 = 0.f;
        #pragma unroll
        for (int j = 0; j < 16; ++j) {
            const int i4 = l8 + j * 8;
            const float4 wv = wrow[i4];
            const float4 a0 = accbuf[0][i4];
            const float4 a1 = accbuf[1][i4];
            const float4 a2 = accbuf[2][i4];
            const float4 a3 = accbuf[3][i4];
            p0 += wv.x*a0.x + wv.y*a0.y + wv.z*a0.z + wv.w*a0.w;
            p1 += wv.x*a1.x + wv.y*a1.y + wv.z*a1.z + wv.w*a1.w;
            p2 += wv.x*a2.x + wv.y*a2.y + wv.z*a2.z + wv.w*a2.w;
            p3 += wv.x*a3.x + wv.y*a3.y + wv.z*a3.z + wv.w*a3.w;
        }
        p0 += __shfl_down(p0, 4, 8); p0 += __shfl_down(p0, 2, 8); p0 += __shfl_down(p0, 1, 8);
        p1 += __shfl_down(p1, 4, 8); p1 += __shfl_down(p1, 2, 8); p1 += __shfl_down(p1, 1, 8);
        p2 += __shfl_down(p2, 4, 8); p2 += __shfl_down(p2, 2, 8); p2 += __shfl_down(p2, 1, 8);
        p3 += __shfl_down(p3, 4, 8); p3 += __shfl_down(p3, 2, 8); p3 += __shfl_down(p3, 1, 8);
        if (l8 == 0) {
            const float bo = l1_b[o];
            x1s[0][o] = fminf(fmaxf(p0 + bo, 0.0f), 1.0f);
            x1s[1][o] = fminf(fmaxf(p1 + bo, 0.0f), 1.0f);
            x1s[2][o] = fminf(fmaxf(p2 + bo, 0.0f), 1.0f);
            x1s[3][o] = fminf(fmaxf(p3 + bo, 0.0f), 1.0f);
        }
    }
    __syncthreads();

    if (t < 128) {
        const int g  = t >> 5;
        const int oo = t & 31;
        const float* __restrict__ wr = l2_w + oo * 32;
        float p = l2_b[oo];
        #pragma unroll
        for (int j = 0; j < 32; ++j) p += x1s[g][j] * wr[j];
        x2s[g][oo] = fminf(fmaxf(p, 0.0f), 1.0f);
    }
    __syncthreads();

    if (t < 4) {
        float p = l3_b[0];
        #pragma unroll
        for (int j = 0; j < 32; ++j) p += x2s[t][j] * l3_w[j];
        out[bb * 4 + t] = p;
    }
}

extern "C" void kernel_launch(void* const* d_in, const int* in_sizes, int n_in,
                              void* d_out, int out_size, void* d_ws, size_t ws_size,
                              hipStream_t stream) {
    const int*   widx = (const int*)d_in[0];
    const int*   bidx = (const int*)d_in[1];
    const float* stm  = (const float*)d_in[2];
    const float* ft_w = (const float*)d_in[3];
    const float* ft_b = (const float*)d_in[4];
    const float* l1_w = (const float*)d_in[5];
    const float* l1_b = (const float*)d_in[6];
    const float* l2_w = (const float*)d_in[7];
    const float* l2_b = (const float*)d_in[8];
    const float* l3_w = (const float*)d_in[9];
    const float* l3_b = (const float*)d_in[10];
    float* out = (float*)d_out;

    if (ws_size >= TBL_BYTES + ACT_BYTES) {
        unsigned short* tbl = (unsigned short*)d_ws;
        float* act = (float*)((char*)d_ws + TBL_BYTES);
        nnue_cvt_kernel<<<dim3(640, 8), 256, 0, stream>>>(ft_w, tbl);
        nnue_ft_kernel<<<(BATCH / 64) * 8, 256, 0, stream>>>(widx, bidx, stm, tbl, ft_b, act);
        nnue_mlp_kernel<<<BATCH / 8, 256, 0, stream>>>(act, l1_w, l1_b, l2_w, l2_b, l3_w, l3_b, out);
    } else {
        nnue_fwd_fallback<<<BATCH / 4, 256, 0, stream>>>(
            widx, bidx, stm, ft_w, ft_b, l1_w, l1_b, l2_w, l2_b, l3_w, l3_b, out);
    }
}

// Round 11
// 152.976 us; speedup vs baseline: 1.0886x; 1.0886x over previous
//
#include <hip/hip_runtime.h>

#define BATCH 32768
#define HID 256
#define ACT 32
#define NROWS 40960

#define TBL_BYTES ((size_t)NROWS * HID * 2)       // 20,971,520 (bf16, group-major)
#define ACT_BYTES ((size_t)BATCH * 512 * 4)       // 67,108,864 (fp32 activations)

typedef float v4f __attribute__((ext_vector_type(4)));

// ============ kernel 0: fp32 [40960][256] -> bf16 group-major [8][40960][32] ============
__global__ __launch_bounds__(256) void nnue_cvt_kernel(
    const float* __restrict__ ft_w, unsigned short* __restrict__ tbl)
{
    const int g  = blockIdx.y;                       // 0..7
    const int tx = blockIdx.x * 256 + threadIdx.x;   // 0 .. 40960*4-1
    const int row = tx >> 2;
    const int c8  = tx & 3;                          // 8-channel chunk within 32-ch group
    const float* __restrict__ src = ft_w + (size_t)row * HID + g * 32 + c8 * 8;
    unsigned int o[8];
    #pragma unroll
    for (int j = 0; j < 8; ++j) {
        unsigned int u = __float_as_uint(src[j]);
        u = u + 0x7FFFu + ((u >> 16) & 1u);          // round-to-nearest-even bf16
        o[j] = u >> 16;
    }
    uint4 pack;
    pack.x = o[0] | (o[1] << 16);
    pack.y = o[2] | (o[3] << 16);
    pack.z = o[4] | (o[5] << 16);
    pack.w = o[6] | (o[7] << 16);
    *(uint4*)(tbl + ((size_t)g * NROWS + row) * 32 + c8 * 8) = pack;
}

// ============ kernel 1: FT gather (round-9 proven: 32 pos x 8 chunks, nt stores) ============
#define LDU2(o) (*(const uint2*)(tg + (unsigned int)(o) + cb))

__global__ __launch_bounds__(256, 8) void nnue_ft_kernel(
    const int* __restrict__ widx, const int* __restrict__ bidx,
    const float* __restrict__ stm,
    const unsigned short* __restrict__ tbl, const float* __restrict__ ft_b,
    float* __restrict__ act)
{
    const int bid = blockIdx.x;
    const int g   = bid & 7;           // column group -> XCD (round-robin dispatch)
    const int pt  = bid >> 3;          // tile of 32 positions
    const int t   = threadIdx.x;
    const int q   = t & 63;
    const int p   = (t >> 6) * 8 + (q >> 3);   // position slot 0..31
    const int c   = q & 7;                     // 4-channel chunk within group

    __shared__ int   soff[32][68];     // byte offsets rowid*64, padded stride
    __shared__ float sstm[32];

    #pragma unroll
    for (int k = 0; k < 4; ++k) {
        const int u  = t + k * 256;            // 0..1023
        const int pp = u >> 5, rr = u & 31;
        soff[pp][rr]      = widx[(size_t)(pt * 32 + pp) * ACT + rr] << 6;
        soff[pp][32 + rr] = bidx[(size_t)(pt * 32 + pp) * ACT + rr] << 6;
    }
    if (t < 32) sstm[t] = stm[pt * 32 + t];
    __syncthreads();

    const char* __restrict__ tg = (const char*)(tbl + (size_t)g * NROWS * 32);
    const unsigned int cb = (unsigned int)(c << 3);
    const int4* __restrict__ sview = (const int4*)(&soff[p][0]);

    float a0=0.f,a1=0.f,a2=0.f,a3=0.f;
    float b0=0.f,b1=0.f,b2=0.f,b3=0.f;

    #pragma unroll
    for (int blk = 0; blk < 4; ++blk) {
        const int4 oA = sview[blk * 2];
        const int4 oB = sview[blk * 2 + 1];
        uint2 v[8];
        v[0] = LDU2(oA.x); v[1] = LDU2(oA.y); v[2] = LDU2(oA.z); v[3] = LDU2(oA.w);
        v[4] = LDU2(oB.x); v[5] = LDU2(oB.y); v[6] = LDU2(oB.z); v[7] = LDU2(oB.w);
        #pragma unroll
        for (int i = 0; i < 8; ++i) {
            a0 += __uint_as_float(v[i].x << 16);
            a1 += __uint_as_float(v[i].x & 0xFFFF0000u);
            a2 += __uint_as_float(v[i].y << 16);
            a3 += __uint_as_float(v[i].y & 0xFFFF0000u);
        }
    }
    #pragma unroll
    for (int blk = 4; blk < 8; ++blk) {
        const int4 oA = sview[blk * 2];
        const int4 oB = sview[blk * 2 + 1];
        uint2 v[8];
        v[0] = LDU2(oA.x); v[1] = LDU2(oA.y); v[2] = LDU2(oA.z); v[3] = LDU2(oA.w);
        v[4] = LDU2(oB.x); v[5] = LDU2(oB.y); v[6] = LDU2(oB.z); v[7] = LDU2(oB.w);
        #pragma unroll
        for (int i = 0; i < 8; ++i) {
            b0 += __uint_as_float(v[i].x << 16);
            b1 += __uint_as_float(v[i].x & 0xFFFF0000u);
            b2 += __uint_as_float(v[i].y << 16);
            b3 += __uint_as_float(v[i].y & 0xFFFF0000u);
        }
    }

    const float4 bv = ((const float4*)ft_b)[g * 8 + c];
    v4f wa, za;
    wa.x = fminf(fmaxf(a0 + bv.x, 0.f), 1.f);
    wa.y = fminf(fmaxf(a1 + bv.y, 0.f), 1.f);
    wa.z = fminf(fmaxf(a2 + bv.z, 0.f), 1.f);
    wa.w = fminf(fmaxf(a3 + bv.w, 0.f), 1.f);
    za.x = fminf(fmaxf(b0 + bv.x, 0.f), 1.f);
    za.y = fminf(fmaxf(b1 + bv.y, 0.f), 1.f);
    za.z = fminf(fmaxf(b2 + bv.z, 0.f), 1.f);
    za.w = fminf(fmaxf(b3 + bv.w, 0.f), 1.f);

    const int  pos = pt * 32 + p;
    const bool s   = (sstm[p] != 0.0f);
    float* dst = act + (size_t)pos * 512 + g * 32 + (c << 2);
    __builtin_nontemporal_store(wa, (v4f*)(dst + (s ? 0 : 256)));
    __builtin_nontemporal_store(za, (v4f*)(dst + (s ? 256 : 0)));
}

// ============ kernel 2: MLP v2 — 16 positions per block, two-pass L1 ============
__global__ __launch_bounds__(256, 4) void nnue_mlp_kernel(
    const float* __restrict__ act,
    const float* __restrict__ l1_w, const float* __restrict__ l1_b,
    const float* __restrict__ l2_w, const float* __restrict__ l2_b,
    const float* __restrict__ l3_w, const float* __restrict__ l3_b,
    float* __restrict__ out)
{
    const int bb = blockIdx.x;       // positions bb*16 .. bb*16+15
    const int t  = threadIdx.x;

    __shared__ float4 sact[16 * 128]; // 16 positions x 512 fp32 = 32 KB
    __shared__ float  x1s[16][33];
    __shared__ float  x2s[16][33];

    const float4* __restrict__ ga = (const float4*)(act + (size_t)bb * 16 * 512);
    #pragma unroll
    for (int k = 0; k < 8; ++k) sact[t + k * 256] = ga[t + k * 256];
    __syncthreads();

    // L1: 32 outputs x 512-dot, 8 threads/output, 16 positions in TWO passes of 8
    // (pacc[8] per pass keeps register pressure at the round-4 proven level;
    //  wrow re-read in pass 2 hits L1).
    {
        const int o  = t >> 3;
        const int l8 = t & 7;
        const float4* __restrict__ wrow = (const float4*)(l1_w + o * 512);
        const float bo = l1_b[o];
        #pragma unroll
        for (int h = 0; h < 2; ++h) {
            float pacc[8] = {0.f,0.f,0.f,0.f,0.f,0.f,0.f,0.f};
            #pragma unroll
            for (int j = 0; j < 16; ++j) {
                const int i4 = l8 + j * 8;
                const float4 wv = wrow[i4];
                #pragma unroll
                for (int p = 0; p < 8; ++p) {
                    const float4 a = sact[(h * 8 + p) * 128 + i4];
                    pacc[p] += wv.x*a.x + wv.y*a.y + wv.z*a.z + wv.w*a.w;
                }
            }
            #pragma unroll
            for (int p = 0; p < 8; ++p) {
                pacc[p] += __shfl_down(pacc[p], 4, 8);
                pacc[p] += __shfl_down(pacc[p], 2, 8);
                pacc[p] += __shfl_down(pacc[p], 1, 8);
            }
            if (l8 == 0) {
                #pragma unroll
                for (int p = 0; p < 8; ++p)
                    x1s[h * 8 + p][o] = fminf(fmaxf(pacc[p] + bo, 0.f), 1.f);
            }
        }
    }
    __syncthreads();

    // L2: 512 (p, oo) pairs over 256 threads, 2 rounds
    #pragma unroll
    for (int h = 0; h < 2; ++h) {
        const int p  = h * 8 + (t >> 5);
        const int oo = t & 31;
        const float* __restrict__ wr = l2_w + oo * 32;
        float s2 = l2_b[oo];
        #pragma unroll
        for (int j = 0; j < 32; ++j) s2 += x1s[p][j] * wr[j];
        x2s[p][oo] = fminf(fmaxf(s2, 0.f), 1.f);
    }
    __syncthreads();

    // L3
    if (t < 16) {
        float s3 = l3_b[0];
        #pragma unroll
        for (int j = 0; j < 32; ++j) s3 += x2s[t][j] * l3_w[j];
        out[bb * 16 + t] = s3;
    }
}

// ============ fallback (round-3 kernel) if ws_size is insufficient ============
__device__ __forceinline__ float4 clip4(float4 v) {
    v.x = fminf(fmaxf(v.x, 0.0f), 1.0f);
    v.y = fminf(fmaxf(v.y, 0.0f), 1.0f);
    v.z = fminf(fmaxf(v.z, 0.0f), 1.0f);
    v.w = fminf(fmaxf(v.w, 0.0f), 1.0f);
    return v;
}
__device__ __forceinline__ void acc4(float4& a, const float4 v) {
    a.x += v.x; a.y += v.y; a.z += v.z; a.w += v.w;
}

__global__ __launch_bounds__(256, 4) void nnue_fwd_fallback(
    const int* __restrict__ widx, const int* __restrict__ bidx,
    const float* __restrict__ stm,
    const float* __restrict__ ft_w, const float* __restrict__ ft_b,
    const float* __restrict__ l1_w, const float* __restrict__ l1_b,
    const float* __restrict__ l2_w, const float* __restrict__ l2_b,
    const float* __restrict__ l3_w, const float* __restrict__ l3_b,
    float* __restrict__ out)
{
    const int bb = blockIdx.x;
    const int t  = threadIdx.x;
    const int w  = t >> 6;
    const int q  = t & 63;

    __shared__ float4 accbuf[4][128];
    __shared__ float  x1s[4][32];
    __shared__ float  x2s[4][32];

    const int pos = bb * 4 + w;
    int myidx;
    if (q < 32) myidx = widx[pos * ACT + q];
    else        myidx = bidx[pos * ACT + (q - 32)];

    const float4* __restrict__ ftw4 = (const float4*)ft_w;
    const float4  bias = ((const float4*)ft_b)[q];
    float4 accW = bias, accB = bias;

    #pragma unroll
    for (int r0 = 0; r0 < 32; r0 += 8) {
        float4 vw[8], vb[8];
        #pragma unroll
        for (int i = 0; i < 8; ++i) {
            const int rw = __builtin_amdgcn_readlane(myidx, r0 + i);
            vw[i] = ftw4[(size_t)rw * 64 + q];
        }
        #pragma unroll
        for (int i = 0; i < 8; ++i) {
            const int rb = __builtin_amdgcn_readlane(myidx, 32 + r0 + i);
            vb[i] = ftw4[(size_t)rb * 64 + q];
        }
        #pragma unroll
        for (int i = 0; i < 8; ++i) { acc4(accW, vw[i]); acc4(accB, vb[i]); }
    }

    const bool s = (stm[pos] != 0.0f);
    accbuf[w][(s ? 0 : 64) + q] = clip4(accW);
    accbuf[w][(s ? 64 : 0) + q] = clip4(accB);
    __syncthreads();

    {
        const int o  = t >> 3;
        const int l8 = t & 7;
        const float4* __restrict__ wrow = (const float4*)(l1_w + o * 512);
        float p0 = 0.f, p1 = 0.f, p2 = 0.f, p3 = 0.f;
        #pragma unroll
        for (int j = 0; j < 16; ++j) {
            const int i4 = l8 + j * 8;
            const float4 wv = wrow[i4];
            const float4 a0 = accbuf[0][i4];
            const float4 a1 = accbuf[1][i4];
            const float4 a2 = accbuf[2][i4];
            const float4 a3 = accbuf[3][i4];
            p0 += wv.x*a0.x + wv.y*a0.y + wv.z*a0.z + wv.w*a0.w;
            p1 += wv.x*a1.x + wv.y*a1.y + wv.z*a1.z + wv.w*a1.w;
            p2 += wv.x*a2.x + wv.y*a2.y + wv.z*a2.z + wv.w*a2.w;
            p3 += wv.x*a3.x + wv.y*a3.y + wv.z*a3.z + wv.w*a3.w;
        }
        p0 += __shfl_down(p0, 4, 8); p0 += __shfl_down(p0, 2, 8); p0 += __shfl_down(p0, 1, 8);
        p1 += __shfl_down(p1, 4, 8); p1 += __shfl_down(p1, 2, 8); p1 += __shfl_down(p1, 1, 8);
        p2 += __shfl_down(p2, 4, 8); p2 += __shfl_down(p2, 2, 8); p2 += __shfl_down(p2, 1, 8);
        p3 += __shfl_down(p3, 4, 8); p3 += __shfl_down(p3, 2, 8); p3 += __shfl_down(p3, 1, 8);
        if (l8 == 0) {
            const float bo = l1_b[o];
            x1s[0][o] = fminf(fmaxf(p0 + bo, 0.0f), 1.0f);
            x1s[1][o] = fminf(fmaxf(p1 + bo, 0.0f), 1.0f);
            x1s[2][o] = fminf(fmaxf(p2 + bo, 0.0f), 1.0f);
            x1s[3][o] = fminf(fmaxf(p3 + bo, 0.0f), 1.0f);
        }
    }
    __syncthreads();

    if (t < 128) {
        const int g  = t >> 5;
        const int oo = t & 31;
        const float* __restrict__ wr = l2_w + oo * 32;
        float p = l2_b[oo];
        #pragma unroll
        for (int j = 0; j < 32; ++j) p += x1s[g][j] * wr[j];
        x2s[g][oo] = fminf(fmaxf(p, 0.0f), 1.0f);
    }
    __syncthreads();

    if (t < 4) {
        float p = l3_b[0];
        #pragma unroll
        for (int j = 0; j < 32; ++j) p += x2s[t][j] * l3_w[j];
        out[bb * 4 + t] = p;
    }
}

extern "C" void kernel_launch(void* const* d_in, const int* in_sizes, int n_in,
                              void* d_out, int out_size, void* d_ws, size_t ws_size,
                              hipStream_t stream) {
    const int*   widx = (const int*)d_in[0];
    const int*   bidx = (const int*)d_in[1];
    const float* stm  = (const float*)d_in[2];
    const float* ft_w = (const float*)d_in[3];
    const float* ft_b = (const float*)d_in[4];
    const float* l1_w = (const float*)d_in[5];
    const float* l1_b = (const float*)d_in[6];
    const float* l2_w = (const float*)d_in[7];
    const float* l2_b = (const float*)d_in[8];
    const float* l3_w = (const float*)d_in[9];
    const float* l3_b = (const float*)d_in[10];
    float* out = (float*)d_out;

    if (ws_size >= TBL_BYTES + ACT_BYTES) {
        unsigned short* tbl = (unsigned short*)d_ws;
        float* act = (float*)((char*)d_ws + TBL_BYTES);
        nnue_cvt_kernel<<<dim3(640, 8), 256, 0, stream>>>(ft_w, tbl);
        nnue_ft_kernel<<<(BATCH / 32) * 8, 256, 0, stream>>>(widx, bidx, stm, tbl, ft_b, act);
        nnue_mlp_kernel<<<BATCH / 16, 256, 0, stream>>>(act, l1_w, l1_b, l2_w, l2_b, l3_w, l3_b, out);
    } else {
        nnue_fwd_fallback<<<BATCH / 4, 256, 0, stream>>>(
            widx, bidx, stm, ft_w, ft_b, l1_w, l1_b, l2_w, l2_b, l3_w, l3_b, out);
    }
}

// Round 12
// 135.924 us; speedup vs baseline: 1.2252x; 1.1255x over previous
//
#include <hip/hip_runtime.h>

#define BATCH 32768
#define HID 256
#define ACT 32
#define NROWS 40960

#define TBL_BYTES ((size_t)NROWS * HID * 2)       // 20,971,520 (bf16, group-major)
#define ACT_BYTES ((size_t)BATCH * 512 * 4)       // 67,108,864 (fp32 activations)

typedef float v4f __attribute__((ext_vector_type(4)));

// ============ kernel 0: fp32 [40960][256] -> bf16 group-major [8][40960][32] ============
__global__ __launch_bounds__(256) void nnue_cvt_kernel(
    const float* __restrict__ ft_w, unsigned short* __restrict__ tbl)
{
    const int g  = blockIdx.y;                       // 0..7
    const int tx = blockIdx.x * 256 + threadIdx.x;   // 0 .. 40960*4-1
    const int row = tx >> 2;
    const int c8  = tx & 3;                          // 8-channel chunk within 32-ch group
    const float* __restrict__ src = ft_w + (size_t)row * HID + g * 32 + c8 * 8;
    unsigned int o[8];
    #pragma unroll
    for (int j = 0; j < 8; ++j) {
        unsigned int u = __float_as_uint(src[j]);
        u = u + 0x7FFFu + ((u >> 16) & 1u);          // round-to-nearest-even bf16
        o[j] = u >> 16;
    }
    uint4 pack;
    pack.x = o[0] | (o[1] << 16);
    pack.y = o[2] | (o[3] << 16);
    pack.z = o[4] | (o[5] << 16);
    pack.w = o[6] | (o[7] << 16);
    *(uint4*)(tbl + ((size_t)g * NROWS + row) * 32 + c8 * 8) = pack;
}

// ============ kernel 1: FT gather (round-9 proven: 32 pos x 8 chunks, nt stores) ============
#define LDU2(o) (*(const uint2*)(tg + (unsigned int)(o) + cb))

__global__ __launch_bounds__(256, 8) void nnue_ft_kernel(
    const int* __restrict__ widx, const int* __restrict__ bidx,
    const float* __restrict__ stm,
    const unsigned short* __restrict__ tbl, const float* __restrict__ ft_b,
    float* __restrict__ act)
{
    const int bid = blockIdx.x;
    const int g   = bid & 7;           // column group -> XCD (round-robin dispatch)
    const int pt  = bid >> 3;          // tile of 32 positions
    const int t   = threadIdx.x;
    const int q   = t & 63;
    const int p   = (t >> 6) * 8 + (q >> 3);   // position slot 0..31
    const int c   = q & 7;                     // 4-channel chunk within group

    __shared__ int   soff[32][68];     // byte offsets rowid*64, padded stride
    __shared__ float sstm[32];

    #pragma unroll
    for (int k = 0; k < 4; ++k) {
        const int u  = t + k * 256;            // 0..1023
        const int pp = u >> 5, rr = u & 31;
        soff[pp][rr]      = widx[(size_t)(pt * 32 + pp) * ACT + rr] << 6;
        soff[pp][32 + rr] = bidx[(size_t)(pt * 32 + pp) * ACT + rr] << 6;
    }
    if (t < 32) sstm[t] = stm[pt * 32 + t];
    __syncthreads();

    const char* __restrict__ tg = (const char*)(tbl + (size_t)g * NROWS * 32);
    const unsigned int cb = (unsigned int)(c << 3);
    const int4* __restrict__ sview = (const int4*)(&soff[p][0]);

    float a0=0.f,a1=0.f,a2=0.f,a3=0.f;
    float b0=0.f,b1=0.f,b2=0.f,b3=0.f;

    #pragma unroll
    for (int blk = 0; blk < 4; ++blk) {
        const int4 oA = sview[blk * 2];
        const int4 oB = sview[blk * 2 + 1];
        uint2 v[8];
        v[0] = LDU2(oA.x); v[1] = LDU2(oA.y); v[2] = LDU2(oA.z); v[3] = LDU2(oA.w);
        v[4] = LDU2(oB.x); v[5] = LDU2(oB.y); v[6] = LDU2(oB.z); v[7] = LDU2(oB.w);
        #pragma unroll
        for (int i = 0; i < 8; ++i) {
            a0 += __uint_as_float(v[i].x << 16);
            a1 += __uint_as_float(v[i].x & 0xFFFF0000u);
            a2 += __uint_as_float(v[i].y << 16);
            a3 += __uint_as_float(v[i].y & 0xFFFF0000u);
        }
    }
    #pragma unroll
    for (int blk = 4; blk < 8; ++blk) {
        const int4 oA = sview[blk * 2];
        const int4 oB = sview[blk * 2 + 1];
        uint2 v[8];
        v[0] = LDU2(oA.x); v[1] = LDU2(oA.y); v[2] = LDU2(oA.z); v[3] = LDU2(oA.w);
        v[4] = LDU2(oB.x); v[5] = LDU2(oB.y); v[6] = LDU2(oB.z); v[7] = LDU2(oB.w);
        #pragma unroll
        for (int i = 0; i < 8; ++i) {
            b0 += __uint_as_float(v[i].x << 16);
            b1 += __uint_as_float(v[i].x & 0xFFFF0000u);
            b2 += __uint_as_float(v[i].y << 16);
            b3 += __uint_as_float(v[i].y & 0xFFFF0000u);
        }
    }

    const float4 bv = ((const float4*)ft_b)[g * 8 + c];
    v4f wa, za;
    wa.x = fminf(fmaxf(a0 + bv.x, 0.f), 1.f);
    wa.y = fminf(fmaxf(a1 + bv.y, 0.f), 1.f);
    wa.z = fminf(fmaxf(a2 + bv.z, 0.f), 1.f);
    wa.w = fminf(fmaxf(a3 + bv.w, 0.f), 1.f);
    za.x = fminf(fmaxf(b0 + bv.x, 0.f), 1.f);
    za.y = fminf(fmaxf(b1 + bv.y, 0.f), 1.f);
    za.z = fminf(fmaxf(b2 + bv.z, 0.f), 1.f);
    za.w = fminf(fmaxf(b3 + bv.w, 0.f), 1.f);

    const int  pos = pt * 32 + p;
    const bool s   = (sstm[p] != 0.0f);
    float* dst = act + (size_t)pos * 512 + g * 32 + (c << 2);
    // Non-temporal: act is write-once streaming; keep the table resident in L2.
    __builtin_nontemporal_store(wa, (v4f*)(dst + (s ? 0 : 256)));
    __builtin_nontemporal_store(za, (v4f*)(dst + (s ? 256 : 0)));
}

// ============ kernel 2: MLP (round-4 proven shape: 8 pos/block, plain loads) ============
__global__ __launch_bounds__(256, 4) void nnue_mlp_kernel(
    const float* __restrict__ act,
    const float* __restrict__ l1_w, const float* __restrict__ l1_b,
    const float* __restrict__ l2_w, const float* __restrict__ l2_b,
    const float* __restrict__ l3_w, const float* __restrict__ l3_b,
    float* __restrict__ out)
{
    const int bb = blockIdx.x;       // positions bb*8 .. bb*8+7
    const int t  = threadIdx.x;

    __shared__ float4 sact[8 * 128]; // 8 positions x 512 fp32 = 16 KB
    __shared__ float  x1s[8][33];
    __shared__ float  x2s[8][33];

    const float4* __restrict__ ga = (const float4*)(act + (size_t)bb * 8 * 512);
    #pragma unroll
    for (int k = 0; k < 4; ++k) sact[t + k * 256] = ga[t + k * 256];
    __syncthreads();

    // L1: 32 outputs x 512-dot, 8 threads/output, 8 positions
    {
        const int o  = t >> 3;
        const int l8 = t & 7;
        const float4* __restrict__ wrow = (const float4*)(l1_w + o * 512);
        float pacc[8] = {0.f,0.f,0.f,0.f,0.f,0.f,0.f,0.f};
        #pragma unroll
        for (int j = 0; j < 16; ++j) {
            const int i4 = l8 + j * 8;
            const float4 wv = wrow[i4];
            #pragma unroll
            for (int p = 0; p < 8; ++p) {
                const float4 a = sact[p * 128 + i4];
                pacc[p] += wv.x*a.x + wv.y*a.y + wv.z*a.z + wv.w*a.w;
            }
        }
        #pragma unroll
        for (int p = 0; p < 8; ++p) {
            pacc[p] += __shfl_down(pacc[p], 4, 8);
            pacc[p] += __shfl_down(pacc[p], 2, 8);
            pacc[p] += __shfl_down(pacc[p], 1, 8);
        }
        if (l8 == 0) {
            const float bo = l1_b[o];
            #pragma unroll
            for (int p = 0; p < 8; ++p)
                x1s[p][o] = fminf(fmaxf(pacc[p] + bo, 0.f), 1.f);
        }
    }
    __syncthreads();

    // L2: 256 threads = 8 positions x 32 outputs
    {
        const int p  = t >> 5;
        const int oo = t & 31;
        const float* __restrict__ wr = l2_w + oo * 32;
        float s2 = l2_b[oo];
        #pragma unroll
        for (int j = 0; j < 32; ++j) s2 += x1s[p][j] * wr[j];
        x2s[p][oo] = fminf(fmaxf(s2, 0.f), 1.f);
    }
    __syncthreads();

    // L3
    if (t < 8) {
        float s3 = l3_b[0];
        #pragma unroll
        for (int j = 0; j < 32; ++j) s3 += x2s[t][j] * l3_w[j];
        out[bb * 8 + t] = s3;
    }
}

// ============ fallback (round-3 kernel) if ws_size is insufficient ============
__device__ __forceinline__ float4 clip4(float4 v) {
    v.x = fminf(fmaxf(v.x, 0.0f), 1.0f);
    v.y = fminf(fmaxf(v.y, 0.0f), 1.0f);
    v.z = fminf(fmaxf(v.z, 0.0f), 1.0f);
    v.w = fminf(fmaxf(v.w, 0.0f), 1.0f);
    return v;
}
__device__ __forceinline__ void acc4(float4& a, const float4 v) {
    a.x += v.x; a.y += v.y; a.z += v.z; a.w += v.w;
}

__global__ __launch_bounds__(256, 4) void nnue_fwd_fallback(
    const int* __restrict__ widx, const int* __restrict__ bidx,
    const float* __restrict__ stm,
    const float* __restrict__ ft_w, const float* __restrict__ ft_b,
    const float* __restrict__ l1_w, const float* __restrict__ l1_b,
    const float* __restrict__ l2_w, const float* __restrict__ l2_b,
    const float* __restrict__ l3_w, const float* __restrict__ l3_b,
    float* __restrict__ out)
{
    const int bb = blockIdx.x;
    const int t  = threadIdx.x;
    const int w  = t >> 6;
    const int q  = t & 63;

    __shared__ float4 accbuf[4][128];
    __shared__ float  x1s[4][32];
    __shared__ float  x2s[4][32];

    const int pos = bb * 4 + w;
    int myidx;
    if (q < 32) myidx = widx[pos * ACT + q];
    else        myidx = bidx[pos * ACT + (q - 32)];

    const float4* __restrict__ ftw4 = (const float4*)ft_w;
    const float4  bias = ((const float4*)ft_b)[q];
    float4 accW = bias, accB = bias;

    #pragma unroll
    for (int r0 = 0; r0 < 32; r0 += 8) {
        float4 vw[8], vb[8];
        #pragma unroll
        for (int i = 0; i < 8; ++i) {
            const int rw = __builtin_amdgcn_readlane(myidx, r0 + i);
            vw[i] = ftw4[(size_t)rw * 64 + q];
        }
        #pragma unroll
        for (int i = 0; i < 8; ++i) {
            const int rb = __builtin_amdgcn_readlane(myidx, 32 + r0 + i);
            vb[i] = ftw4[(size_t)rb * 64 + q];
        }
        #pragma unroll
        for (int i = 0; i < 8; ++i) { acc4(accW, vw[i]); acc4(accB, vb[i]); }
    }

    const bool s = (stm[pos] != 0.0f);
    accbuf[w][(s ? 0 : 64) + q] = clip4(accW);
    accbuf[w][(s ? 64 : 0) + q] = clip4(accB);
    __syncthreads();

    {
        const int o  = t >> 3;
        const int l8 = t & 7;
        const float4* __restrict__ wrow = (const float4*)(l1_w + o * 512);
        float p0 = 0.f, p1 = 0.f, p2 = 0.f, p3 = 0.f;
        #pragma unroll
        for (int j = 0; j < 16; ++j) {
            const int i4 = l8 + j * 8;
            const float4 wv = wrow[i4];
            const float4 a0 = accbuf[0][i4];
            const float4 a1 = accbuf[1][i4];
            const float4 a2 = accbuf[2][i4];
            const float4 a3 = accbuf[3][i4];
            p0 += wv.x*a0.x + wv.y*a0.y + wv.z*a0.z + wv.w*a0.w;
            p1 += wv.x*a1.x + wv.y*a1.y + wv.z*a1.z + wv.w*a1.w;
            p2 += wv.x*a2.x + wv.y*a2.y + wv.z*a2.z + wv.w*a2.w;
            p3 += wv.x*a3.x + wv.y*a3.y + wv.z*a3.z + wv.w*a3.w;
        }
        p0 += __shfl_down(p0, 4, 8); p0 += __shfl_down(p0, 2, 8); p0 += __shfl_down(p0, 1, 8);
        p1 += __shfl_down(p1, 4, 8); p1 += __shfl_down(p1, 2, 8); p1 += __shfl_down(p1, 1, 8);
        p2 += __shfl_down(p2, 4, 8); p2 += __shfl_down(p2, 2, 8); p2 += __shfl_down(p2, 1, 8);
        p3 += __shfl_down(p3, 4, 8); p3 += __shfl_down(p3, 2, 8); p3 += __shfl_down(p3, 1, 8);
        if (l8 == 0) {
            const float bo = l1_b[o];
            x1s[0][o] = fminf(fmaxf(p0 + bo, 0.0f), 1.0f);
            x1s[1][o] = fminf(fmaxf(p1 + bo, 0.0f), 1.0f);
            x1s[2][o] = fminf(fmaxf(p2 + bo, 0.0f), 1.0f);
            x1s[3][o] = fminf(fmaxf(p3 + bo, 0.0f), 1.0f);
        }
    }
    __syncthreads();

    if (t < 128) {
        const int g  = t >> 5;
        const int oo = t & 31;
        const float* __restrict__ wr = l2_w + oo * 32;
        float p = l2_b[oo];
        #pragma unroll
        for (int j = 0; j < 32; ++j) p += x1s[g][j] * wr[j];
        x2s[g][oo] = fminf(fmaxf(p, 0.0f), 1.0f);
    }
    __syncthreads();

    if (t < 4) {
        float p = l3_b[0];
        #pragma unroll
        for (int j = 0; j < 32; ++j) p += x2s[t][j] * l3_w[j];
        out[bb * 4 + t] = p;
    }
}

extern "C" void kernel_launch(void* const* d_in, const int* in_sizes, int n_in,
                              void* d_out, int out_size, void* d_ws, size_t ws_size,
                              hipStream_t stream) {
    const int*   widx = (const int*)d_in[0];
    const int*   bidx = (const int*)d_in[1];
    const float* stm  = (const float*)d_in[2];
    const float* ft_w = (const float*)d_in[3];
    const float* ft_b = (const float*)d_in[4];
    const float* l1_w = (const float*)d_in[5];
    const float* l1_b = (const float*)d_in[6];
    const float* l2_w = (const float*)d_in[7];
    const float* l2_b = (const float*)d_in[8];
    const float* l3_w = (const float*)d_in[9];
    const float* l3_b = (const float*)d_in[10];
    float* out = (float*)d_out;

    if (ws_size >= TBL_BYTES + ACT_BYTES) {
        unsigned short* tbl = (unsigned short*)d_ws;
        float* act = (float*)((char*)d_ws + TBL_BYTES);
        nnue_cvt_kernel<<<dim3(640, 8), 256, 0, stream>>>(ft_w, tbl);
        nnue_ft_kernel<<<(BATCH / 32) * 8, 256, 0, stream>>>(widx, bidx, stm, tbl, ft_b, act);
        nnue_mlp_kernel<<<BATCH / 8, 256, 0, stream>>>(act, l1_w, l1_b, l2_w, l2_b, l3_w, l3_b, out);
    } else {
        nnue_fwd_fallback<<<BATCH / 4, 256, 0, stream>>>(
            widx, bidx, stm, ft_w, ft_b, l1_w, l1_b, l2_w, l2_b, l3_w, l3_b, out);
    }
}

// Round 13
// 131.516 us; speedup vs baseline: 1.2663x; 1.0335x over previous
//
#include <hip/hip_runtime.h>

#define BATCH 32768
#define HID 256
#define ACT 32
#define NROWS 40960

#define TBL_BYTES ((size_t)NROWS * HID * 2)       // 20,971,520 (bf16, group-major)
#define ACT_BYTES ((size_t)BATCH * 512 * 4)       // 67,108,864 (fp32 activations)

// ============ kernel 0: fp32 [40960][256] -> bf16 group-major [8][40960][32] ============
__global__ __launch_bounds__(256) void nnue_cvt_kernel(
    const float* __restrict__ ft_w, unsigned short* __restrict__ tbl)
{
    const int g  = blockIdx.y;                       // 0..7
    const int tx = blockIdx.x * 256 + threadIdx.x;   // 0 .. 40960*4-1
    const int row = tx >> 2;
    const int c8  = tx & 3;                          // 8-channel chunk within 32-ch group
    const float* __restrict__ src = ft_w + (size_t)row * HID + g * 32 + c8 * 8;
    unsigned int o[8];
    #pragma unroll
    for (int j = 0; j < 8; ++j) {
        unsigned int u = __float_as_uint(src[j]);
        u = u + 0x7FFFu + ((u >> 16) & 1u);          // round-to-nearest-even bf16
        o[j] = u >> 16;
    }
    uint4 pack;
    pack.x = o[0] | (o[1] << 16);
    pack.y = o[2] | (o[3] << 16);
    pack.z = o[4] | (o[5] << 16);
    pack.w = o[6] | (o[7] << 16);
    *(uint4*)(tbl + ((size_t)g * NROWS + row) * 32 + c8 * 8) = pack;
}

// ============ kernel 1: FT gather (32 pos x 8 chunks, PLAIN act stores) ============
#define LDU2(o) (*(const uint2*)(tg + (unsigned int)(o) + cb))

__global__ __launch_bounds__(256, 8) void nnue_ft_kernel(
    const int* __restrict__ widx, const int* __restrict__ bidx,
    const float* __restrict__ stm,
    const unsigned short* __restrict__ tbl, const float* __restrict__ ft_b,
    float* __restrict__ act)
{
    const int bid = blockIdx.x;
    const int g   = bid & 7;           // column group -> XCD (round-robin dispatch)
    const int pt  = bid >> 3;          // tile of 32 positions
    const int t   = threadIdx.x;
    const int q   = t & 63;
    const int p   = (t >> 6) * 8 + (q >> 3);   // position slot 0..31
    const int c   = q & 7;                     // 4-channel chunk within group

    __shared__ int   soff[32][68];     // byte offsets rowid*64, padded stride
    __shared__ float sstm[32];

    #pragma unroll
    for (int k = 0; k < 4; ++k) {
        const int u  = t + k * 256;            // 0..1023
        const int pp = u >> 5, rr = u & 31;
        soff[pp][rr]      = widx[(size_t)(pt * 32 + pp) * ACT + rr] << 6;
        soff[pp][32 + rr] = bidx[(size_t)(pt * 32 + pp) * ACT + rr] << 6;
    }
    if (t < 32) sstm[t] = stm[pt * 32 + t];
    __syncthreads();

    const char* __restrict__ tg = (const char*)(tbl + (size_t)g * NROWS * 32);
    const unsigned int cb = (unsigned int)(c << 3);
    const int4* __restrict__ sview = (const int4*)(&soff[p][0]);

    float a0=0.f,a1=0.f,a2=0.f,a3=0.f;
    float b0=0.f,b1=0.f,b2=0.f,b3=0.f;

    #pragma unroll
    for (int blk = 0; blk < 4; ++blk) {
        const int4 oA = sview[blk * 2];
        const int4 oB = sview[blk * 2 + 1];
        uint2 v[8];
        v[0] = LDU2(oA.x); v[1] = LDU2(oA.y); v[2] = LDU2(oA.z); v[3] = LDU2(oA.w);
        v[4] = LDU2(oB.x); v[5] = LDU2(oB.y); v[6] = LDU2(oB.z); v[7] = LDU2(oB.w);
        #pragma unroll
        for (int i = 0; i < 8; ++i) {
            a0 += __uint_as_float(v[i].x << 16);
            a1 += __uint_as_float(v[i].x & 0xFFFF0000u);
            a2 += __uint_as_float(v[i].y << 16);
            a3 += __uint_as_float(v[i].y & 0xFFFF0000u);
        }
    }
    #pragma unroll
    for (int blk = 4; blk < 8; ++blk) {
        const int4 oA = sview[blk * 2];
        const int4 oB = sview[blk * 2 + 1];
        uint2 v[8];
        v[0] = LDU2(oA.x); v[1] = LDU2(oA.y); v[2] = LDU2(oA.z); v[3] = LDU2(oA.w);
        v[4] = LDU2(oB.x); v[5] = LDU2(oB.y); v[6] = LDU2(oB.z); v[7] = LDU2(oB.w);
        #pragma unroll
        for (int i = 0; i < 8; ++i) {
            b0 += __uint_as_float(v[i].x << 16);
            b1 += __uint_as_float(v[i].x & 0xFFFF0000u);
            b2 += __uint_as_float(v[i].y << 16);
            b3 += __uint_as_float(v[i].y & 0xFFFF0000u);
        }
    }

    const float4 bv = ((const float4*)ft_b)[g * 8 + c];
    float4 wa, za;
    wa.x = fminf(fmaxf(a0 + bv.x, 0.f), 1.f);
    wa.y = fminf(fmaxf(a1 + bv.y, 0.f), 1.f);
    wa.z = fminf(fmaxf(a2 + bv.z, 0.f), 1.f);
    wa.w = fminf(fmaxf(a3 + bv.w, 0.f), 1.f);
    za.x = fminf(fmaxf(b0 + bv.x, 0.f), 1.f);
    za.y = fminf(fmaxf(b1 + bv.y, 0.f), 1.f);
    za.z = fminf(fmaxf(b2 + bv.z, 0.f), 1.f);
    za.w = fminf(fmaxf(b3 + bv.w, 0.f), 1.f);

    const int  pos = pt * 32 + p;
    const bool s   = (sstm[p] != 0.0f);
    float* dst = act + (size_t)pos * 512 + g * 32 + (c << 2);
    // Plain stores: act lines stay in L2 so the MLP's reads hit L2 (r4 vs r12 A/B).
    *(float4*)(dst + (s ? 0 : 256)) = wa;
    *(float4*)(dst + (s ? 256 : 0)) = za;
}

// ============ kernel 2: MLP (round-4 proven shape: 8 pos/block, plain loads) ============
__global__ __launch_bounds__(256, 4) void nnue_mlp_kernel(
    const float* __restrict__ act,
    const float* __restrict__ l1_w, const float* __restrict__ l1_b,
    const float* __restrict__ l2_w, const float* __restrict__ l2_b,
    const float* __restrict__ l3_w, const float* __restrict__ l3_b,
    float* __restrict__ out)
{
    const int bb = blockIdx.x;       // positions bb*8 .. bb*8+7
    const int t  = threadIdx.x;

    __shared__ float4 sact[8 * 128]; // 8 positions x 512 fp32 = 16 KB
    __shared__ float  x1s[8][33];
    __shared__ float  x2s[8][33];

    const float4* __restrict__ ga = (const float4*)(act + (size_t)bb * 8 * 512);
    #pragma unroll
    for (int k = 0; k < 4; ++k) sact[t + k * 256] = ga[t + k * 256];
    __syncthreads();

    // L1: 32 outputs x 512-dot, 8 threads/output, 8 positions
    {
        const int o  = t >> 3;
        const int l8 = t & 7;
        const float4* __restrict__ wrow = (const float4*)(l1_w + o * 512);
        float pacc[8] = {0.f,0.f,0.f,0.f,0.f,0.f,0.f,0.f};
        #pragma unroll
        for (int j = 0; j < 16; ++j) {
            const int i4 = l8 + j * 8;
            const float4 wv = wrow[i4];
            #pragma unroll
            for (int p = 0; p < 8; ++p) {
                const float4 a = sact[p * 128 + i4];
                pacc[p] += wv.x*a.x + wv.y*a.y + wv.z*a.z + wv.w*a.w;
            }
        }
        #pragma unroll
        for (int p = 0; p < 8; ++p) {
            pacc[p] += __shfl_down(pacc[p], 4, 8);
            pacc[p] += __shfl_down(pacc[p], 2, 8);
            pacc[p] += __shfl_down(pacc[p], 1, 8);
        }
        if (l8 == 0) {
            const float bo = l1_b[o];
            #pragma unroll
            for (int p = 0; p < 8; ++p)
                x1s[p][o] = fminf(fmaxf(pacc[p] + bo, 0.f), 1.f);
        }
    }
    __syncthreads();

    // L2: 256 threads = 8 positions x 32 outputs
    {
        const int p  = t >> 5;
        const int oo = t & 31;
        const float* __restrict__ wr = l2_w + oo * 32;
        float s2 = l2_b[oo];
        #pragma unroll
        for (int j = 0; j < 32; ++j) s2 += x1s[p][j] * wr[j];
        x2s[p][oo] = fminf(fmaxf(s2, 0.f), 1.f);
    }
    __syncthreads();

    // L3
    if (t < 8) {
        float s3 = l3_b[0];
        #pragma unroll
        for (int j = 0; j < 32; ++j) s3 += x2s[t][j] * l3_w[j];
        out[bb * 8 + t] = s3;
    }
}

// ============ fallback (round-3 kernel) if ws_size is insufficient ============
__device__ __forceinline__ float4 clip4(float4 v) {
    v.x = fminf(fmaxf(v.x, 0.0f), 1.0f);
    v.y = fminf(fmaxf(v.y, 0.0f), 1.0f);
    v.z = fminf(fmaxf(v.z, 0.0f), 1.0f);
    v.w = fminf(fmaxf(v.w, 0.0f), 1.0f);
    return v;
}
__device__ __forceinline__ void acc4(float4& a, const float4 v) {
    a.x += v.x; a.y += v.y; a.z += v.z; a.w += v.w;
}

__global__ __launch_bounds__(256, 4) void nnue_fwd_fallback(
    const int* __restrict__ widx, const int* __restrict__ bidx,
    const float* __restrict__ stm,
    const float* __restrict__ ft_w, const float* __restrict__ ft_b,
    const float* __restrict__ l1_w, const float* __restrict__ l1_b,
    const float* __restrict__ l2_w, const float* __restrict__ l2_b,
    const float* __restrict__ l3_w, const float* __restrict__ l3_b,
    float* __restrict__ out)
{
    const int bb = blockIdx.x;
    const int t  = threadIdx.x;
    const int w  = t >> 6;
    const int q  = t & 63;

    __shared__ float4 accbuf[4][128];
    __shared__ float  x1s[4][32];
    __shared__ float  x2s[4][32];

    const int pos = bb * 4 + w;
    int myidx;
    if (q < 32) myidx = widx[pos * ACT + q];
    else        myidx = bidx[pos * ACT + (q - 32)];

    const float4* __restrict__ ftw4 = (const float4*)ft_w;
    const float4  bias = ((const float4*)ft_b)[q];
    float4 accW = bias, accB = bias;

    #pragma unroll
    for (int r0 = 0; r0 < 32; r0 += 8) {
        float4 vw[8], vb[8];
        #pragma unroll
        for (int i = 0; i < 8; ++i) {
            const int rw = __builtin_amdgcn_readlane(myidx, r0 + i);
            vw[i] = ftw4[(size_t)rw * 64 + q];
        }
        #pragma unroll
        for (int i = 0; i < 8; ++i) {
            const int rb = __builtin_amdgcn_readlane(myidx, 32 + r0 + i);
            vb[i] = ftw4[(size_t)rb * 64 + q];
        }
        #pragma unroll
        for (int i = 0; i < 8; ++i) { acc4(accW, vw[i]); acc4(accB, vb[i]); }
    }

    const bool s = (stm[pos] != 0.0f);
    accbuf[w][(s ? 0 : 64) + q] = clip4(accW);
    accbuf[w][(s ? 64 : 0) + q] = clip4(accB);
    __syncthreads();

    {
        const int o  = t >> 3;
        const int l8 = t & 7;
        const float4* __restrict__ wrow = (const float4*)(l1_w + o * 512);
        float p0 = 0.f, p1 = 0.f, p2 = 0.f, p3 = 0.f;
        #pragma unroll
        for (int j = 0; j < 16; ++j) {
            const int i4 = l8 + j * 8;
            const float4 wv = wrow[i4];
            const float4 a0 = accbuf[0][i4];
            const float4 a1 = accbuf[1][i4];
            const float4 a2 = accbuf[2][i4];
            const float4 a3 = accbuf[3][i4];
            p0 += wv.x*a0.x + wv.y*a0.y + wv.z*a0.z + wv.w*a0.w;
            p1 += wv.x*a1.x + wv.y*a1.y + wv.z*a1.z + wv.w*a1.w;
            p2 += wv.x*a2.x + wv.y*a2.y + wv.z*a2.z + wv.w*a2.w;
            p3 += wv.x*a3.x + wv.y*a3.y + wv.z*a3.z + wv.w*a3.w;
        }
        p0 += __shfl_down(p0, 4, 8); p0 += __shfl_down(p0, 2, 8); p0 += __shfl_down(p0, 1, 8);
        p1 += __shfl_down(p1, 4, 8); p1 += __shfl_down(p1, 2, 8); p1 += __shfl_down(p1, 1, 8);
        p2 += __shfl_down(p2, 4, 8); p2 += __shfl_down(p2, 2, 8); p2 += __shfl_down(p2, 1, 8);
        p3 += __shfl_down(p3, 4, 8); p3 += __shfl_down(p3, 2, 8); p3 += __shfl_down(p3, 1, 8);
        if (l8 == 0) {
            const float bo = l1_b[o];
            x1s[0][o] = fminf(fmaxf(p0 + bo, 0.0f), 1.0f);
            x1s[1][o] = fminf(fmaxf(p1 + bo, 0.0f), 1.0f);
            x1s[2][o] = fminf(fmaxf(p2 + bo, 0.0f), 1.0f);
            x1s[3][o] = fminf(fmaxf(p3 + bo, 0.0f), 1.0f);
        }
    }
    __syncthreads();

    if (t < 128) {
        const int g  = t >> 5;
        const int oo = t & 31;
        const float* __restrict__ wr = l2_w + oo * 32;
        float p = l2_b[oo];
        #pragma unroll
        for (int j = 0; j < 32; ++j) p += x1s[g][j] * wr[j];
        x2s[g][oo] = fminf(fmaxf(p, 0.0f), 1.0f);
    }
    __syncthreads();

    if (t < 4) {
        float p = l3_b[0];
        #pragma unroll
        for (int j = 0; j < 32; ++j) p += x2s[t][j] * l3_w[j];
        out[bb * 4 + t] = p;
    }
}

extern "C" void kernel_launch(void* const* d_in, const int* in_sizes, int n_in,
                              void* d_out, int out_size, void* d_ws, size_t ws_size,
                              hipStream_t stream) {
    const int*   widx = (const int*)d_in[0];
    const int*   bidx = (const int*)d_in[1];
    const float* stm  = (const float*)d_in[2];
    const float* ft_w = (const float*)d_in[3];
    const float* ft_b = (const float*)d_in[4];
    const float* l1_w = (const float*)d_in[5];
    const float* l1_b = (const float*)d_in[6];
    const float* l2_w = (const float*)d_in[7];
    const float* l2_b = (const float*)d_in[8];
    const float* l3_w = (const float*)d_in[9];
    const float* l3_b = (const float*)d_in[10];
    float* out = (float*)d_out;

    if (ws_size >= TBL_BYTES + ACT_BYTES) {
        unsigned short* tbl = (unsigned short*)d_ws;
        float* act = (float*)((char*)d_ws + TBL_BYTES);
        nnue_cvt_kernel<<<dim3(640, 8), 256, 0, stream>>>(ft_w, tbl);
        nnue_ft_kernel<<<(BATCH / 32) * 8, 256, 0, stream>>>(widx, bidx, stm, tbl, ft_b, act);
        nnue_mlp_kernel<<<BATCH / 8, 256, 0, stream>>>(act, l1_w, l1_b, l2_w, l2_b, l3_w, l3_b, out);
    } else {
        nnue_fwd_fallback<<<BATCH / 4, 256, 0, stream>>>(
            widx, bidx, stm, ft_w, ft_b, l1_w, l1_b, l2_w, l2_b, l3_w, l3_b, out);
    }
}